// Round 6
// baseline (615.128 us; speedup 1.0000x reference)
//
#include <hip/hip_runtime.h>

#define IN_CH 1024
#define INTER 512
#define NEXP  128
#define TPE   512

typedef __bf16 bf16x8  __attribute__((ext_vector_type(8)));
typedef float  f32x4   __attribute__((ext_vector_type(4)));

// Phase scaffolding: barrier orders issue; lgkmcnt(0) drains this wave's ds
// ops; sched_barrier stops MFMA hoisting past the wait (rule #18); setprio
// keeps the matrix pipe favored (T5). Only pays when >=2 blocks/CU (R5 A/B).
#define PHASE_SYNC() do { \
  __builtin_amdgcn_s_barrier(); \
  asm volatile("s_waitcnt lgkmcnt(0)" ::: "memory"); \
  __builtin_amdgcn_sched_barrier(0); \
  __builtin_amdgcn_s_setprio(1); } while (0)
#define PHASE_END() do { \
  __builtin_amdgcn_s_setprio(0); \
  __builtin_amdgcn_s_barrier(); } while (0)

// ---------------- Kernel A: h = silu(x@w1^T + b1) * (x@w3^T + b3) ------------
// BM=64 tok x BN=128 f, BK=64, 512 thr / 8 waves (2 wm x 4 wn).
// LDS 80 KB (sA 16 + sB1 32 + sB3 32, all dbuf) -> 2 blocks/CU.
// 2 phases per K-tile (ks halves); stores(t+1) in p0, loads(t+2) in p1.
__global__ __launch_bounds__(512) void moe_h_kernel(
    const float* __restrict__ x, const int* __restrict__ idxs,
    const float* __restrict__ w1w, const float* __restrict__ w1b,
    const float* __restrict__ w3w, const float* __restrict__ w3b,
    __bf16* __restrict__ hbuf)
{
  __shared__ __align__(16) ushort sA [2][64*64];
  __shared__ __align__(16) ushort sB1[2][128*64];
  __shared__ __align__(16) ushort sB3[2][128*64];   // 80 KB total

  // XCD swizzle: 4096 blocks, 512/XCD -> each expert's 32 tiles on one XCD
  const int blk = (blockIdx.x & 7) * (NEXP*32/8) + (blockIdx.x >> 3);
  const int e   = blk >> 5;
  const int tl  = blk & 31;
  const int tm  = tl >> 2, tn = tl & 3;   // tm 0..7 (64-tok), tn 0..3 (128-f)

  const int tid  = threadIdx.x;
  const int lane = tid & 63;
  const int wid  = tid >> 6;
  const int wm   = wid >> 2;       // 0..1 -> 32-row slice
  const int wn   = wid & 3;        // 0..3 -> 32-col slice

  // staging: thread owns (row, 16B-chunk c); 8 chunks per 64-elem row
  const int row = tid >> 3;        // 0..63
  const int c   = tid & 7;         // 0..7
  const int sro = row*64 + ((c ^ (row&7))<<3);   // ushort offset, swizzled

  const int tok = idxs[e*TPE + tm*64 + row];
  const float* apx = x   + (size_t)tok*IN_CH + (c<<3);
  const float* b1p = w1w + ((size_t)e*INTER + tn*128 + row)*IN_CH + (c<<3);
  const float* b3p = w3w + ((size_t)e*INTER + tn*128 + row)*IN_CH + (c<<3);

  f32x4 acc1[2][2], acc3[2][2];
#pragma unroll
  for (int a = 0; a < 2; ++a)
#pragma unroll
    for (int b = 0; b < 2; ++b) {
      acc1[a][b] = (f32x4){0.f,0.f,0.f,0.f};
      acc3[a][b] = (f32x4){0.f,0.f,0.f,0.f};
    }

  float4 xa, xb, w1v[4], w3v[4];   // 10 float4 staging

  auto loads = [&](int kof) {
    xa = *(const float4*)(apx + kof);
    xb = *(const float4*)(apx + kof + 4);
#pragma unroll
    for (int i = 0; i < 2; ++i) {
      w1v[2*i]   = *(const float4*)(b1p + (size_t)(64*i)*IN_CH + kof);
      w1v[2*i+1] = *(const float4*)(b1p + (size_t)(64*i)*IN_CH + kof + 4);
      w3v[2*i]   = *(const float4*)(b3p + (size_t)(64*i)*IN_CH + kof);
      w3v[2*i+1] = *(const float4*)(b3p + (size_t)(64*i)*IN_CH + kof + 4);
    }
  };
  auto cvt8 = [](const float4& lo, const float4& hi) {
    bf16x8 r;
    r[0]=(__bf16)lo.x; r[1]=(__bf16)lo.y; r[2]=(__bf16)lo.z; r[3]=(__bf16)lo.w;
    r[4]=(__bf16)hi.x; r[5]=(__bf16)hi.y; r[6]=(__bf16)hi.z; r[7]=(__bf16)hi.w;
    return r;
  };
  auto stores = [&](int buf) {
    *(bf16x8*)&sA[buf][sro] = cvt8(xa, xb);
#pragma unroll
    for (int i = 0; i < 2; ++i) {
      *(bf16x8*)&sB1[buf][i*64*64 + sro] = cvt8(w1v[2*i], w1v[2*i+1]);
      *(bf16x8*)&sB3[buf][i*64*64 + sro] = cvt8(w3v[2*i], w3v[2*i+1]);
    }
  };
  auto rdA = [&](int buf, int ks, bf16x8 af[2]) {
    const int k8 = (ks<<2) + (lane>>4);
#pragma unroll
    for (int mi = 0; mi < 2; ++mi) {
      const int r = wm*32 + mi*16 + (lane&15);
      af[mi] = *(const bf16x8*)&sA[buf][r*64 + ((k8 ^ (r&7))<<3)];
    }
  };
  auto rdB = [&](int buf, int ks, bf16x8 bq[2], bf16x8 bt[2]) {
    const int k8 = (ks<<2) + (lane>>4);
#pragma unroll
    for (int ni = 0; ni < 2; ++ni) {
      const int r   = wn*32 + ni*16 + (lane&15);
      const int off = r*64 + ((k8 ^ (r&7))<<3);
      bq[ni] = *(const bf16x8*)&sB1[buf][off];
      bt[ni] = *(const bf16x8*)&sB3[buf][off];
    }
  };

  // prologue
  loads(0);
  stores(0);
  loads(64);
  asm volatile("s_waitcnt lgkmcnt(0)" ::: "memory");
  __builtin_amdgcn_s_barrier();

  int cur = 0;
  const int NT = IN_CH/64;
  for (int kt = 0; kt < NT; ++kt) {
    bf16x8 af[2], bq[2], bt[2];

    // phase 0: ks=0 + cvt/ds_write of tile t+1
    rdA(cur, 0, af);
    rdB(cur, 0, bq, bt);
    if (kt < NT - 1) stores(cur ^ 1);
    PHASE_SYNC();
#pragma unroll
    for (int mi = 0; mi < 2; ++mi)
#pragma unroll
      for (int ni = 0; ni < 2; ++ni) {
        acc1[mi][ni] = __builtin_amdgcn_mfma_f32_16x16x32_bf16(af[mi], bq[ni], acc1[mi][ni], 0, 0, 0);
        acc3[mi][ni] = __builtin_amdgcn_mfma_f32_16x16x32_bf16(af[mi], bt[ni], acc3[mi][ni], 0, 0, 0);
      }
    PHASE_END();

    // phase 1: ks=1 + issue loads of tile t+2
    rdA(cur, 1, af);
    rdB(cur, 1, bq, bt);
    if (kt < NT - 2) loads((kt+2)*64);
    PHASE_SYNC();
#pragma unroll
    for (int mi = 0; mi < 2; ++mi)
#pragma unroll
      for (int ni = 0; ni < 2; ++ni) {
        acc1[mi][ni] = __builtin_amdgcn_mfma_f32_16x16x32_bf16(af[mi], bq[ni], acc1[mi][ni], 0, 0, 0);
        acc3[mi][ni] = __builtin_amdgcn_mfma_f32_16x16x32_bf16(af[mi], bt[ni], acc3[mi][ni], 0, 0, 0);
      }
    PHASE_END();

    cur ^= 1;
  }

  // epilogue: bias + SwiGLU, store bf16 h tile
  const int rowbase = tm*64  + wm*32;
  const int colbase = tn*128 + wn*32;
#pragma unroll
  for (int ni = 0; ni < 2; ++ni) {
    const int fc = colbase + ni*16 + (lane&15);
    const float b1v = w1b[e*INTER + fc];
    const float b3v = w3b[e*INTER + fc];
#pragma unroll
    for (int mi = 0; mi < 2; ++mi) {
#pragma unroll
      for (int j = 0; j < 4; ++j) {
        const int rl = rowbase + mi*16 + ((lane>>4)<<2) + j;
        const float h1 = acc1[mi][ni][j] + b1v;
        const float h3 = acc3[mi][ni][j] + b3v;
        const float s  = h1 / (1.0f + __expf(-h1));
        hbuf[((size_t)e*TPE + rl)*INTER + fc] = (__bf16)(s * h3);
      }
    }
  }
}

// ---------------- Kernel B: out = h @ w2^T + b2, scattered via idxs ----------
// Unchanged from R5 (2 blocks/CU, 2 phases/K-tile, ~127 us).
__global__ __launch_bounds__(512) void moe_out_kernel(
    const __bf16* __restrict__ hbuf, const float* __restrict__ w2w,
    const float* __restrict__ w2b, const int* __restrict__ idxs,
    float* __restrict__ out)
{
  __shared__ __align__(16) ushort sA[2][128*64];
  __shared__ __align__(16) ushort sB[2][128*64];

  const int blk = (blockIdx.x & 7) * (NEXP*32/8) + (blockIdx.x >> 3);
  const int e   = blk >> 5;
  const int tl  = blk & 31;
  const int tm  = tl >> 3, tn = tl & 7;

  const int tid  = threadIdx.x;
  const int lane = tid & 63;
  const int wid  = tid >> 6;
  const int wm   = wid >> 1;       // 0..3
  const int wn   = wid & 1;        // 0..1

  const int rA   = tid >> 3;          // 0..63
  const int c8   = tid & 7;           // 0..7
  const int swzA = ((c8 ^ (rA&7))<<3);
  const __bf16* ap = hbuf + ((size_t)e*TPE + tm*128 + rA)*INTER + (c8<<3);

  const int r0   = tid >> 4;          // 0..31
  const int c4   = tid & 15;
  const int swzB = ((((c4>>1) ^ (r0&7))<<3) | ((c4&1)<<2));
  const float* bp = w2w + ((size_t)e*IN_CH + tn*128 + r0)*INTER + (c4<<2);

  f32x4 acc[2][4];
#pragma unroll
  for (int a = 0; a < 2; ++a)
#pragma unroll
    for (int b = 0; b < 4; ++b) acc[a][b] = (f32x4){0.f,0.f,0.f,0.f};

  uint4  hv[2];
  float4 wv[4];

  auto loads = [&](int kof) {
#pragma unroll
    for (int i = 0; i < 2; ++i)
      hv[i] = *(const uint4*)(ap + (size_t)(64*i)*INTER + kof);
#pragma unroll
    for (int i = 0; i < 4; ++i)
      wv[i] = *(const float4*)(bp + (size_t)(32*i)*INTER + kof);
  };
  auto stores = [&](int buf) {
#pragma unroll
    for (int i = 0; i < 2; ++i)
      *(uint4*)&sA[buf][(rA + 64*i)*64 + swzA] = hv[i];
#pragma unroll
    for (int i = 0; i < 4; ++i) {
      typedef __bf16 bf16x4v __attribute__((ext_vector_type(4)));
      bf16x4v b;
      b[0]=(__bf16)wv[i].x; b[1]=(__bf16)wv[i].y; b[2]=(__bf16)wv[i].z; b[3]=(__bf16)wv[i].w;
      *(bf16x4v*)&sB[buf][(r0 + 32*i)*64 + swzB] = b;
    }
  };
  auto rdA = [&](int buf, int ks, bf16x8 af[2]) {
    const int k8 = (ks<<2) + (lane>>4);
#pragma unroll
    for (int mi = 0; mi < 2; ++mi) {
      const int r = wm*32 + mi*16 + (lane&15);
      af[mi] = *(const bf16x8*)&sA[buf][r*64 + ((k8 ^ (r&7))<<3)];
    }
  };
  auto rdB = [&](int buf, int ks, bf16x8 bfr[4]) {
    const int k8 = (ks<<2) + (lane>>4);
#pragma unroll
    for (int ni = 0; ni < 4; ++ni) {
      const int r = wn*64 + ni*16 + (lane&15);
      bfr[ni] = *(const bf16x8*)&sB[buf][r*64 + ((k8 ^ (r&7))<<3)];
    }
  };

  loads(0);
  stores(0);
  loads(64);
  asm volatile("s_waitcnt lgkmcnt(0)" ::: "memory");
  __builtin_amdgcn_s_barrier();

  int cur = 0;
  const int NT = INTER/64;
  for (int kt = 0; kt < NT; ++kt) {
    bf16x8 af[2], bfr[4];

    rdA(cur, 0, af);
    rdB(cur, 0, bfr);
    if (kt < NT - 1) stores(cur ^ 1);
    PHASE_SYNC();
#pragma unroll
    for (int mi = 0; mi < 2; ++mi)
#pragma unroll
      for (int ni = 0; ni < 4; ++ni)
        acc[mi][ni] = __builtin_amdgcn_mfma_f32_16x16x32_bf16(af[mi], bfr[ni], acc[mi][ni], 0, 0, 0);
    PHASE_END();

    rdA(cur, 1, af);
    rdB(cur, 1, bfr);
    if (kt < NT - 2) loads((kt+2)*64);
    PHASE_SYNC();
#pragma unroll
    for (int mi = 0; mi < 2; ++mi)
#pragma unroll
      for (int ni = 0; ni < 4; ++ni)
        acc[mi][ni] = __builtin_amdgcn_mfma_f32_16x16x32_bf16(af[mi], bfr[ni], acc[mi][ni], 0, 0, 0);
    PHASE_END();

    cur ^= 1;
  }

  const int rowbase = tm*128 + wm*32;
  const int colbase = tn*128 + wn*64;
  float b2v[4];
#pragma unroll
  for (int ni = 0; ni < 4; ++ni)
    b2v[ni] = w2b[e*IN_CH + colbase + ni*16 + (lane&15)];
#pragma unroll
  for (int mi = 0; mi < 2; ++mi) {
#pragma unroll
    for (int j = 0; j < 4; ++j) {
      const int rl  = rowbase + mi*16 + ((lane>>4)<<2) + j;
      const int tok = idxs[e*TPE + rl];
      float* orow = out + (size_t)tok*IN_CH;
#pragma unroll
      for (int ni = 0; ni < 4; ++ni)
        orow[colbase + ni*16 + (lane&15)] = acc[mi][ni][j] + b2v[ni];
    }
  }
}

extern "C" void kernel_launch(void* const* d_in, const int* in_sizes, int n_in,
                              void* d_out, int out_size, void* d_ws, size_t ws_size,
                              hipStream_t stream) {
  const float* x    = (const float*)d_in[0];
  const int*   idxs = (const int*)d_in[1];
  const float* w1w  = (const float*)d_in[2];
  const float* w1b  = (const float*)d_in[3];
  const float* w2w  = (const float*)d_in[4];
  const float* w2b  = (const float*)d_in[5];
  const float* w3w  = (const float*)d_in[6];
  const float* w3b  = (const float*)d_in[7];
  float*  out  = (float*)d_out;
  __bf16* hbuf = (__bf16*)d_ws;   // 128*512*512 bf16 = 64 MB intermediate

  moe_h_kernel<<<dim3(NEXP*32), dim3(512), 0, stream>>>(x, idxs, w1w, w1b, w3w, w3b, hbuf);
  moe_out_kernel<<<dim3(NEXP*32), dim3(512), 0, stream>>>(hbuf, w2w, w2b, idxs, out);
}

// Round 7
// 517.999 us; speedup vs baseline: 1.1875x; 1.1875x over previous
//
#include <hip/hip_runtime.h>

#define IN_CH 1024
#define INTER 512
#define NEXP  128
#define TPE   512

typedef __bf16 bf16x8  __attribute__((ext_vector_type(8)));
typedef float  f32x4   __attribute__((ext_vector_type(4)));

// Phase scaffolding: barrier orders issue; lgkmcnt(0) drains this wave's ds
// ops; sched_barrier stops MFMA hoisting past the wait (rule #18); setprio
// favors the matrix pipe (T5). Pays only at >=2 blocks/CU (R5 A/B evidence).
#define PHASE_SYNC() do { \
  __builtin_amdgcn_s_barrier(); \
  asm volatile("s_waitcnt lgkmcnt(0)" ::: "memory"); \
  __builtin_amdgcn_sched_barrier(0); \
  __builtin_amdgcn_s_setprio(1); } while (0)
#define PHASE_END() do { \
  __builtin_amdgcn_s_setprio(0); \
  __builtin_amdgcn_s_barrier(); } while (0)

// ---------------- Kernel A: h = silu(x@w1^T + b1) * (x@w3^T + b3) ------------
// BM=128 tok x BN=64 f, BK=64; LDS 64 KB (sA 32 + sB1 16 + sB3 16, dbuf)
// -> 2 blocks/CU. waves_per_eu(4,4) pins the compiler at the 128-VGPR /
// 4-waves-per-EU point (R4/R6 lesson: heuristic squeeze to 64 VGPR sinks the
// prefetch loads into the stores and serializes the pipeline).
__global__ __launch_bounds__(512)
__attribute__((amdgpu_waves_per_eu(4, 4)))
void moe_h_kernel(
    const float* __restrict__ x, const int* __restrict__ idxs,
    const float* __restrict__ w1w, const float* __restrict__ w1b,
    const float* __restrict__ w3w, const float* __restrict__ w3b,
    __bf16* __restrict__ hbuf)
{
  __shared__ __align__(16) ushort sA [2][128*64];
  __shared__ __align__(16) ushort sB1[2][64*64];
  __shared__ __align__(16) ushort sB3[2][64*64];   // 64 KB total

  // XCD swizzle: 4096 blocks, 512/XCD
  const int blk = (blockIdx.x & 7) * (NEXP*32/8) + (blockIdx.x >> 3);
  const int e   = blk >> 5;
  const int tl  = blk & 31;
  const int tm  = tl >> 3, tn = tl & 7;   // tm 0..3 (128 tok), tn 0..7 (64 f)

  const int tid  = threadIdx.x;
  const int lane = tid & 63;
  const int wid  = tid >> 6;
  const int wm   = wid >> 1;       // 0..3 -> 32-row slice
  const int wn   = wid & 1;        // 0..1 -> 32-col slice

  // staging: A rows rA and rA+64 (chunk c); B1/B3 row rA (chunk c)
  const int rA = tid >> 3;         // 0..63
  const int c  = tid & 7;          // 0..7 (16B chunks, 8 per 64-elem row)
  const int swzc = ((c ^ (rA&7))<<3);          // (rA+64)&7 == rA&7
  const int sroA0 = rA*64 + swzc;
  const int sroA1 = (rA+64)*64 + swzc;
  const int sroB  = rA*64 + swzc;

  const int tok0 = idxs[e*TPE + tm*128 + rA];
  const int tok1 = idxs[e*TPE + tm*128 + rA + 64];
  const float* ap0 = x + (size_t)tok0*IN_CH + (c<<3);
  const float* ap1 = x + (size_t)tok1*IN_CH + (c<<3);
  const float* b1p = w1w + ((size_t)e*INTER + tn*64 + rA)*IN_CH + (c<<3);
  const float* b3p = w3w + ((size_t)e*INTER + tn*64 + rA)*IN_CH + (c<<3);

  f32x4 acc1[2][2], acc3[2][2];
#pragma unroll
  for (int a = 0; a < 2; ++a)
#pragma unroll
    for (int b = 0; b < 2; ++b) {
      acc1[a][b] = (f32x4){0.f,0.f,0.f,0.f};
      acc3[a][b] = (f32x4){0.f,0.f,0.f,0.f};
    }

  float4 x0a, x0b, x1a, x1b, w1a, w1b_, w3a, w3b_;   // 8 float4 staging

  auto loads = [&](int kof) {
    x0a  = *(const float4*)(ap0 + kof);
    x0b  = *(const float4*)(ap0 + kof + 4);
    x1a  = *(const float4*)(ap1 + kof);
    x1b  = *(const float4*)(ap1 + kof + 4);
    w1a  = *(const float4*)(b1p + kof);
    w1b_ = *(const float4*)(b1p + kof + 4);
    w3a  = *(const float4*)(b3p + kof);
    w3b_ = *(const float4*)(b3p + kof + 4);
  };
  auto cvt8 = [](const float4& lo, const float4& hi) {
    bf16x8 r;
    r[0]=(__bf16)lo.x; r[1]=(__bf16)lo.y; r[2]=(__bf16)lo.z; r[3]=(__bf16)lo.w;
    r[4]=(__bf16)hi.x; r[5]=(__bf16)hi.y; r[6]=(__bf16)hi.z; r[7]=(__bf16)hi.w;
    return r;
  };
  auto stores = [&](int buf) {
    *(bf16x8*)&sA [buf][sroA0] = cvt8(x0a, x0b);
    *(bf16x8*)&sA [buf][sroA1] = cvt8(x1a, x1b);
    *(bf16x8*)&sB1[buf][sroB]  = cvt8(w1a, w1b_);
    *(bf16x8*)&sB3[buf][sroB]  = cvt8(w3a, w3b_);
  };
  auto rdA = [&](int buf, int ks, bf16x8 af[2]) {
    const int k8 = (ks<<2) + (lane>>4);
#pragma unroll
    for (int mi = 0; mi < 2; ++mi) {
      const int r = wm*32 + mi*16 + (lane&15);
      af[mi] = *(const bf16x8*)&sA[buf][r*64 + ((k8 ^ (r&7))<<3)];
    }
  };
  auto rdB = [&](int buf, int ks, bf16x8 bq[2], bf16x8 bt[2]) {
    const int k8 = (ks<<2) + (lane>>4);
#pragma unroll
    for (int ni = 0; ni < 2; ++ni) {
      const int r   = wn*32 + ni*16 + (lane&15);
      const int off = r*64 + ((k8 ^ (r&7))<<3);
      bq[ni] = *(const bf16x8*)&sB1[buf][off];
      bt[ni] = *(const bf16x8*)&sB3[buf][off];
    }
  };

  // prologue
  loads(0);
  stores(0);
  loads(64);
  asm volatile("s_waitcnt lgkmcnt(0)" ::: "memory");
  __builtin_amdgcn_s_barrier();

  int cur = 0;
  const int NT = IN_CH/64;
  for (int kt = 0; kt < NT; ++kt) {
    bf16x8 af[2], bq[2], bt[2];

    // phase 0: ks=0 + cvt/ds_write of tile t+1
    rdA(cur, 0, af);
    rdB(cur, 0, bq, bt);
    if (kt < NT - 1) stores(cur ^ 1);
    PHASE_SYNC();
#pragma unroll
    for (int mi = 0; mi < 2; ++mi)
#pragma unroll
      for (int ni = 0; ni < 2; ++ni) {
        acc1[mi][ni] = __builtin_amdgcn_mfma_f32_16x16x32_bf16(af[mi], bq[ni], acc1[mi][ni], 0, 0, 0);
        acc3[mi][ni] = __builtin_amdgcn_mfma_f32_16x16x32_bf16(af[mi], bt[ni], acc3[mi][ni], 0, 0, 0);
      }
    PHASE_END();

    // phase 1: ks=1 + issue loads of tile t+2
    rdA(cur, 1, af);
    rdB(cur, 1, bq, bt);
    if (kt < NT - 2) loads((kt+2)*64);
    PHASE_SYNC();
#pragma unroll
    for (int mi = 0; mi < 2; ++mi)
#pragma unroll
      for (int ni = 0; ni < 2; ++ni) {
        acc1[mi][ni] = __builtin_amdgcn_mfma_f32_16x16x32_bf16(af[mi], bq[ni], acc1[mi][ni], 0, 0, 0);
        acc3[mi][ni] = __builtin_amdgcn_mfma_f32_16x16x32_bf16(af[mi], bt[ni], acc3[mi][ni], 0, 0, 0);
      }
    PHASE_END();

    cur ^= 1;
  }

  // epilogue: bias + SwiGLU, store bf16 h tile
  const int rowbase = tm*128 + wm*32;
  const int colbase = tn*64  + wn*32;
#pragma unroll
  for (int ni = 0; ni < 2; ++ni) {
    const int fc = colbase + ni*16 + (lane&15);
    const float b1v = w1b[e*INTER + fc];
    const float b3v = w3b[e*INTER + fc];
#pragma unroll
    for (int mi = 0; mi < 2; ++mi) {
#pragma unroll
      for (int j = 0; j < 4; ++j) {
        const int rl = rowbase + mi*16 + ((lane>>4)<<2) + j;
        const float h1 = acc1[mi][ni][j] + b1v;
        const float h3 = acc3[mi][ni][j] + b3v;
        const float s  = h1 / (1.0f + __expf(-h1));
        hbuf[((size_t)e*TPE + rl)*INTER + fc] = (__bf16)(s * h3);
      }
    }
  }
}

// ---------------- Kernel B: out = h @ w2^T + b2, scattered via idxs ----------
// Unchanged from R5 (2 blocks/CU, 2 phases/K-tile, ~127 us, 541 TF).
__global__ __launch_bounds__(512) void moe_out_kernel(
    const __bf16* __restrict__ hbuf, const float* __restrict__ w2w,
    const float* __restrict__ w2b, const int* __restrict__ idxs,
    float* __restrict__ out)
{
  __shared__ __align__(16) ushort sA[2][128*64];
  __shared__ __align__(16) ushort sB[2][128*64];

  const int blk = (blockIdx.x & 7) * (NEXP*32/8) + (blockIdx.x >> 3);
  const int e   = blk >> 5;
  const int tl  = blk & 31;
  const int tm  = tl >> 3, tn = tl & 7;

  const int tid  = threadIdx.x;
  const int lane = tid & 63;
  const int wid  = tid >> 6;
  const int wm   = wid >> 1;       // 0..3
  const int wn   = wid & 1;        // 0..1

  const int rA   = tid >> 3;          // 0..63
  const int c8   = tid & 7;           // 0..7
  const int swzA = ((c8 ^ (rA&7))<<3);
  const __bf16* ap = hbuf + ((size_t)e*TPE + tm*128 + rA)*INTER + (c8<<3);

  const int r0   = tid >> 4;          // 0..31
  const int c4   = tid & 15;
  const int swzB = ((((c4>>1) ^ (r0&7))<<3) | ((c4&1)<<2));
  const float* bp = w2w + ((size_t)e*IN_CH + tn*128 + r0)*INTER + (c4<<2);

  f32x4 acc[2][4];
#pragma unroll
  for (int a = 0; a < 2; ++a)
#pragma unroll
    for (int b = 0; b < 4; ++b) acc[a][b] = (f32x4){0.f,0.f,0.f,0.f};

  uint4  hv[2];
  float4 wv[4];

  auto loads = [&](int kof) {
#pragma unroll
    for (int i = 0; i < 2; ++i)
      hv[i] = *(const uint4*)(ap + (size_t)(64*i)*INTER + kof);
#pragma unroll
    for (int i = 0; i < 4; ++i)
      wv[i] = *(const float4*)(bp + (size_t)(32*i)*INTER + kof);
  };
  auto stores = [&](int buf) {
#pragma unroll
    for (int i = 0; i < 2; ++i)
      *(uint4*)&sA[buf][(rA + 64*i)*64 + swzA] = hv[i];
#pragma unroll
    for (int i = 0; i < 4; ++i) {
      typedef __bf16 bf16x4v __attribute__((ext_vector_type(4)));
      bf16x4v b;
      b[0]=(__bf16)wv[i].x; b[1]=(__bf16)wv[i].y; b[2]=(__bf16)wv[i].z; b[3]=(__bf16)wv[i].w;
      *(bf16x4v*)&sB[buf][(r0 + 32*i)*64 + swzB] = b;
    }
  };
  auto rdA = [&](int buf, int ks, bf16x8 af[2]) {
    const int k8 = (ks<<2) + (lane>>4);
#pragma unroll
    for (int mi = 0; mi < 2; ++mi) {
      const int r = wm*32 + mi*16 + (lane&15);
      af[mi] = *(const bf16x8*)&sA[buf][r*64 + ((k8 ^ (r&7))<<3)];
    }
  };
  auto rdB = [&](int buf, int ks, bf16x8 bfr[4]) {
    const int k8 = (ks<<2) + (lane>>4);
#pragma unroll
    for (int ni = 0; ni < 4; ++ni) {
      const int r = wn*64 + ni*16 + (lane&15);
      bfr[ni] = *(const bf16x8*)&sB[buf][r*64 + ((k8 ^ (r&7))<<3)];
    }
  };

  loads(0);
  stores(0);
  loads(64);
  asm volatile("s_waitcnt lgkmcnt(0)" ::: "memory");
  __builtin_amdgcn_s_barrier();

  int cur = 0;
  const int NT = INTER/64;
  for (int kt = 0; kt < NT; ++kt) {
    bf16x8 af[2], bfr[4];

    rdA(cur, 0, af);
    rdB(cur, 0, bfr);
    if (kt < NT - 1) stores(cur ^ 1);
    PHASE_SYNC();
#pragma unroll
    for (int mi = 0; mi < 2; ++mi)
#pragma unroll
      for (int ni = 0; ni < 4; ++ni)
        acc[mi][ni] = __builtin_amdgcn_mfma_f32_16x16x32_bf16(af[mi], bfr[ni], acc[mi][ni], 0, 0, 0);
    PHASE_END();

    rdA(cur, 1, af);
    rdB(cur, 1, bfr);
    if (kt < NT - 2) loads((kt+2)*64);
    PHASE_SYNC();
#pragma unroll
    for (int mi = 0; mi < 2; ++mi)
#pragma unroll
      for (int ni = 0; ni < 4; ++ni)
        acc[mi][ni] = __builtin_amdgcn_mfma_f32_16x16x32_bf16(af[mi], bfr[ni], acc[mi][ni], 0, 0, 0);
    PHASE_END();

    cur ^= 1;
  }

  const int rowbase = tm*128 + wm*32;
  const int colbase = tn*128 + wn*64;
  float b2v[4];
#pragma unroll
  for (int ni = 0; ni < 4; ++ni)
    b2v[ni] = w2b[e*IN_CH + colbase + ni*16 + (lane&15)];
#pragma unroll
  for (int mi = 0; mi < 2; ++mi) {
#pragma unroll
    for (int j = 0; j < 4; ++j) {
      const int rl  = rowbase + mi*16 + ((lane>>4)<<2) + j;
      const int tok = idxs[e*TPE + rl];
      float* orow = out + (size_t)tok*IN_CH;
#pragma unroll
      for (int ni = 0; ni < 4; ++ni)
        orow[colbase + ni*16 + (lane&15)] = acc[mi][ni][j] + b2v[ni];
    }
  }
}

extern "C" void kernel_launch(void* const* d_in, const int* in_sizes, int n_in,
                              void* d_out, int out_size, void* d_ws, size_t ws_size,
                              hipStream_t stream) {
  const float* x    = (const float*)d_in[0];
  const int*   idxs = (const int*)d_in[1];
  const float* w1w  = (const float*)d_in[2];
  const float* w1b  = (const float*)d_in[3];
  const float* w2w  = (const float*)d_in[4];
  const float* w2b  = (const float*)d_in[5];
  const float* w3w  = (const float*)d_in[6];
  const float* w3b  = (const float*)d_in[7];
  float*  out  = (float*)d_out;
  __bf16* hbuf = (__bf16*)d_ws;   // 128*512*512 bf16 = 64 MB intermediate

  moe_h_kernel<<<dim3(NEXP*32), dim3(512), 0, stream>>>(x, idxs, w1w, w1b, w3w, w3b, hbuf);
  moe_out_kernel<<<dim3(NEXP*32), dim3(512), 0, stream>>>(hbuf, w2w, w2b, idxs, out);
}

// Round 10
// 489.679 us; speedup vs baseline: 1.2562x; 1.0578x over previous
//
#include <hip/hip_runtime.h>

#define IN_CH 1024
#define INTER 512
#define NEXP  128
#define TPE   512

typedef __bf16 bf16x8  __attribute__((ext_vector_type(8)));
typedef float  f32x4   __attribute__((ext_vector_type(4)));

// Paired ISA-level staging load: both 16B halves from one base pointer
// (offset:16 immediate) -> no address temps. "=&v" early-clobber keeps dst
// off the addr pair (R8 abort). asm volatile ordering pins issue before the
// phase barrier; dst liveness to stores() prevents sinking (R4/R6/R7).
// Pressure discipline: the ONLY safe mode for asm-def regs is "never
// spilled" -- compiler can't know a pending VMEM targets them (R9 NaN).
#define GLOAD2(d0, d1, p) \
  asm volatile("global_load_dwordx4 %0, %2, off\n\t" \
               "global_load_dwordx4 %1, %2, off offset:16" \
               : "=&v"(d0), "=&v"(d1) : "v"(p))

// Wait for staging loads, then FENCE the scheduler: hipcc hoists
// register-only v_cvt above inline-asm s_waitcnt despite "memory" (rule #18).
#define VM_WAIT() do { \
  asm volatile("s_waitcnt vmcnt(0)" ::: "memory"); \
  __builtin_amdgcn_sched_barrier(0); } while (0)

#define PHASE_SYNC() do { \
  __builtin_amdgcn_s_barrier(); \
  asm volatile("s_waitcnt lgkmcnt(0)" ::: "memory"); \
  __builtin_amdgcn_sched_barrier(0); \
  __builtin_amdgcn_s_setprio(1); } while (0)
#define PHASE_END() do { \
  __builtin_amdgcn_s_setprio(0); \
  __builtin_amdgcn_s_barrier(); } while (0)

// ---------------- Kernel A: h = silu(x@w1^T + b1) * (x@w3^T + b3) ------------
// BM=128 tok x BN=64 f, BK=64; LDS 64 KB dbuf -> 2 blocks/CU.
// p0: {rd ks0 | vmcnt+stores(t+1) | issue loads(t+2)}, p1: {rd ks1}.
// Self-advancing pointers (+64 floats/K-tile) keep addressing at 4 VGPR pairs.
__global__ __launch_bounds__(512)
__attribute__((amdgpu_waves_per_eu(4, 4)))
void moe_h_kernel(
    const float* __restrict__ x, const int* __restrict__ idxs,
    const float* __restrict__ w1w, const float* __restrict__ w1b,
    const float* __restrict__ w3w, const float* __restrict__ w3b,
    __bf16* __restrict__ hbuf)
{
  __shared__ __align__(16) ushort sA [2][128*64];
  __shared__ __align__(16) ushort sB1[2][64*64];
  __shared__ __align__(16) ushort sB3[2][64*64];   // 64 KB total

  const int blk = (blockIdx.x & 7) * (NEXP*32/8) + (blockIdx.x >> 3);
  const int e   = blk >> 5;
  const int tl  = blk & 31;
  const int tm  = tl >> 3, tn = tl & 7;   // tm 0..3 (128 tok), tn 0..7 (64 f)

  const int tid  = threadIdx.x;
  const int lane = tid & 63;
  const int wid  = tid >> 6;
  const int wm   = wid >> 1;       // 0..3 -> 32-row slice
  const int wn   = wid & 1;        // 0..1 -> 32-col slice

  const int rA = tid >> 3;         // 0..63
  const int c  = tid & 7;          // 0..7 (16B bf16 chunks per 64-elem row)
  const int swzc  = ((c ^ (rA&7))<<3);
  const int sroA0 = rA*64 + swzc;
  const int sroA1 = (rA+64)*64 + swzc;
  const int sroB  = rA*64 + swzc;

  const int tok0 = idxs[e*TPE + tm*128 + rA];
  const int tok1 = idxs[e*TPE + tm*128 + rA + 64];
  const float* ap0 = x + (size_t)tok0*IN_CH + (c<<3);
  const float* ap1 = x + (size_t)tok1*IN_CH + (c<<3);
  const float* b1p = w1w + ((size_t)e*INTER + tn*64 + rA)*IN_CH + (c<<3);
  const float* b3p = w3w + ((size_t)e*INTER + tn*64 + rA)*IN_CH + (c<<3);

  f32x4 acc1[2][2], acc3[2][2];
#pragma unroll
  for (int a = 0; a < 2; ++a)
#pragma unroll
    for (int b = 0; b < 2; ++b) {
      acc1[a][b] = (f32x4){0.f,0.f,0.f,0.f};
      acc3[a][b] = (f32x4){0.f,0.f,0.f,0.f};
    }

  f32x4 x0a, x0b, x1a, x1b, w1a, w1b_, w3a, w3b_;   // 32 staging VGPRs

  auto loads = [&]() {       // issue batch at current pointers, then advance
    GLOAD2(x0a, x0b, ap0);
    GLOAD2(x1a, x1b, ap1);
    GLOAD2(w1a, w1b_, b1p);
    GLOAD2(w3a, w3b_, b3p);
    ap0 += 64; ap1 += 64; b1p += 64; b3p += 64;
  };
  auto cvt8 = [](const f32x4& lo, const f32x4& hi) {
    bf16x8 r;
    r[0]=(__bf16)lo[0]; r[1]=(__bf16)lo[1]; r[2]=(__bf16)lo[2]; r[3]=(__bf16)lo[3];
    r[4]=(__bf16)hi[0]; r[5]=(__bf16)hi[1]; r[6]=(__bf16)hi[2]; r[7]=(__bf16)hi[3];
    return r;
  };
  auto stores = [&](int buf) {
    VM_WAIT();
    *(bf16x8*)&sA [buf][sroA0] = cvt8(x0a, x0b);
    *(bf16x8*)&sA [buf][sroA1] = cvt8(x1a, x1b);
    *(bf16x8*)&sB1[buf][sroB]  = cvt8(w1a, w1b_);
    *(bf16x8*)&sB3[buf][sroB]  = cvt8(w3a, w3b_);
  };
  auto rdA = [&](int buf, int ks, bf16x8 af[2]) {
    const int k8 = (ks<<2) + (lane>>4);
#pragma unroll
    for (int mi = 0; mi < 2; ++mi) {
      const int r = wm*32 + mi*16 + (lane&15);
      af[mi] = *(const bf16x8*)&sA[buf][r*64 + ((k8 ^ (r&7))<<3)];
    }
  };
  auto rdB = [&](int buf, int ks, bf16x8 bq[2], bf16x8 bt[2]) {
    const int k8 = (ks<<2) + (lane>>4);
#pragma unroll
    for (int ni = 0; ni < 2; ++ni) {
      const int r   = wn*32 + ni*16 + (lane&15);
      const int off = r*64 + ((k8 ^ (r&7))<<3);
      bq[ni] = *(const bf16x8*)&sB1[buf][off];
      bt[ni] = *(const bf16x8*)&sB3[buf][off];
    }
  };

  // prologue: tile0 staged, tile1 in flight
  loads();
  stores(0);
  loads();
  asm volatile("s_waitcnt lgkmcnt(0)" ::: "memory");
  __builtin_amdgcn_s_barrier();

  int cur = 0;
  const int NT = IN_CH/64;
  for (int kt = 0; kt < NT; ++kt) {
    bf16x8 af[2], bq[2], bt[2];

    // phase 0: ks=0 | stores(t+1) | issue loads(t+2)
    rdA(cur, 0, af);
    rdB(cur, 0, bq, bt);
    if (kt < NT - 1) stores(cur ^ 1);
    if (kt < NT - 2) loads();
    PHASE_SYNC();
#pragma unroll
    for (int mi = 0; mi < 2; ++mi)
#pragma unroll
      for (int ni = 0; ni < 2; ++ni) {
        acc1[mi][ni] = __builtin_amdgcn_mfma_f32_16x16x32_bf16(af[mi], bq[ni], acc1[mi][ni], 0, 0, 0);
        acc3[mi][ni] = __builtin_amdgcn_mfma_f32_16x16x32_bf16(af[mi], bt[ni], acc3[mi][ni], 0, 0, 0);
      }
    PHASE_END();

    // phase 1: ks=1
    rdA(cur, 1, af);
    rdB(cur, 1, bq, bt);
    PHASE_SYNC();
#pragma unroll
    for (int mi = 0; mi < 2; ++mi)
#pragma unroll
      for (int ni = 0; ni < 2; ++ni) {
        acc1[mi][ni] = __builtin_amdgcn_mfma_f32_16x16x32_bf16(af[mi], bq[ni], acc1[mi][ni], 0, 0, 0);
        acc3[mi][ni] = __builtin_amdgcn_mfma_f32_16x16x32_bf16(af[mi], bt[ni], acc3[mi][ni], 0, 0, 0);
      }
    PHASE_END();

    cur ^= 1;
  }

  // epilogue: bias + SwiGLU, store bf16 h tile
  const int rowbase = tm*128 + wm*32;
  const int colbase = tn*64  + wn*32;
#pragma unroll
  for (int ni = 0; ni < 2; ++ni) {
    const int fc = colbase + ni*16 + (lane&15);
    const float b1v = w1b[e*INTER + fc];
    const float b3v = w3b[e*INTER + fc];
#pragma unroll
    for (int mi = 0; mi < 2; ++mi) {
#pragma unroll
      for (int j = 0; j < 4; ++j) {
        const int rl = rowbase + mi*16 + ((lane>>4)<<2) + j;
        const float h1 = acc1[mi][ni][j] + b1v;
        const float h3 = acc3[mi][ni][j] + b3v;
        const float s  = h1 / (1.0f + __expf(-h1));
        hbuf[((size_t)e*TPE + rl)*INTER + fc] = (__bf16)(s * h3);
      }
    }
  }
}

// ---------------- Kernel B: out = h @ w2^T + b2, scattered via idxs ----------
// R5 VERBATIM (plain HIP loads, no waves_per_eu): proven ~127 us, 541 TF.
__global__ __launch_bounds__(512) void moe_out_kernel(
    const __bf16* __restrict__ hbuf, const float* __restrict__ w2w,
    const float* __restrict__ w2b, const int* __restrict__ idxs,
    float* __restrict__ out)
{
  __shared__ __align__(16) ushort sA[2][128*64];
  __shared__ __align__(16) ushort sB[2][128*64];

  const int blk = (blockIdx.x & 7) * (NEXP*32/8) + (blockIdx.x >> 3);
  const int e   = blk >> 5;
  const int tl  = blk & 31;
  const int tm  = tl >> 3, tn = tl & 7;

  const int tid  = threadIdx.x;
  const int lane = tid & 63;
  const int wid  = tid >> 6;
  const int wm   = wid >> 1;       // 0..3
  const int wn   = wid & 1;        // 0..1

  const int rA   = tid >> 3;          // 0..63
  const int c8   = tid & 7;           // 0..7
  const int swzA = ((c8 ^ (rA&7))<<3);
  const __bf16* ap = hbuf + ((size_t)e*TPE + tm*128 + rA)*INTER + (c8<<3);

  const int r0   = tid >> 4;          // 0..31
  const int c4   = tid & 15;
  const int swzB = ((((c4>>1) ^ (r0&7))<<3) | ((c4&1)<<2));
  const float* bp = w2w + ((size_t)e*IN_CH + tn*128 + r0)*INTER + (c4<<2);

  f32x4 acc[2][4];
#pragma unroll
  for (int a = 0; a < 2; ++a)
#pragma unroll
    for (int b = 0; b < 4; ++b) acc[a][b] = (f32x4){0.f,0.f,0.f,0.f};

  uint4  hv[2];
  float4 wv[4];

  auto loads = [&](int kof) {
#pragma unroll
    for (int i = 0; i < 2; ++i)
      hv[i] = *(const uint4*)(ap + (size_t)(64*i)*INTER + kof);
#pragma unroll
    for (int i = 0; i < 4; ++i)
      wv[i] = *(const float4*)(bp + (size_t)(32*i)*INTER + kof);
  };
  auto stores = [&](int buf) {
#pragma unroll
    for (int i = 0; i < 2; ++i)
      *(uint4*)&sA[buf][(rA + 64*i)*64 + swzA] = hv[i];
#pragma unroll
    for (int i = 0; i < 4; ++i) {
      typedef __bf16 bf16x4v __attribute__((ext_vector_type(4)));
      bf16x4v b;
      b[0]=(__bf16)wv[i].x; b[1]=(__bf16)wv[i].y; b[2]=(__bf16)wv[i].z; b[3]=(__bf16)wv[i].w;
      *(bf16x4v*)&sB[buf][(r0 + 32*i)*64 + swzB] = b;
    }
  };
  auto rdA = [&](int buf, int ks, bf16x8 af[2]) {
    const int k8 = (ks<<2) + (lane>>4);
#pragma unroll
    for (int mi = 0; mi < 2; ++mi) {
      const int r = wm*32 + mi*16 + (lane&15);
      af[mi] = *(const bf16x8*)&sA[buf][r*64 + ((k8 ^ (r&7))<<3)];
    }
  };
  auto rdB = [&](int buf, int ks, bf16x8 bfr[4]) {
    const int k8 = (ks<<2) + (lane>>4);
#pragma unroll
    for (int ni = 0; ni < 4; ++ni) {
      const int r = wn*64 + ni*16 + (lane&15);
      bfr[ni] = *(const bf16x8*)&sB[buf][r*64 + ((k8 ^ (r&7))<<3)];
    }
  };

  loads(0);
  stores(0);
  loads(64);
  asm volatile("s_waitcnt lgkmcnt(0)" ::: "memory");
  __builtin_amdgcn_s_barrier();

  int cur = 0;
  const int NT = INTER/64;
  for (int kt = 0; kt < NT; ++kt) {
    bf16x8 af[2], bfr[4];

    rdA(cur, 0, af);
    rdB(cur, 0, bfr);
    if (kt < NT - 1) stores(cur ^ 1);
    PHASE_SYNC();
#pragma unroll
    for (int mi = 0; mi < 2; ++mi)
#pragma unroll
      for (int ni = 0; ni < 4; ++ni)
        acc[mi][ni] = __builtin_amdgcn_mfma_f32_16x16x32_bf16(af[mi], bfr[ni], acc[mi][ni], 0, 0, 0);
    PHASE_END();

    rdA(cur, 1, af);
    rdB(cur, 1, bfr);
    if (kt < NT - 2) loads((kt+2)*64);
    PHASE_SYNC();
#pragma unroll
    for (int mi = 0; mi < 2; ++mi)
#pragma unroll
      for (int ni = 0; ni < 4; ++ni)
        acc[mi][ni] = __builtin_amdgcn_mfma_f32_16x16x32_bf16(af[mi], bfr[ni], acc[mi][ni], 0, 0, 0);
    PHASE_END();

    cur ^= 1;
  }

  const int rowbase = tm*128 + wm*32;
  const int colbase = tn*128 + wn*64;
  float b2v[4];
#pragma unroll
  for (int ni = 0; ni < 4; ++ni)
    b2v[ni] = w2b[e*IN_CH + colbase + ni*16 + (lane&15)];
#pragma unroll
  for (int mi = 0; mi < 2; ++mi) {
#pragma unroll
    for (int j = 0; j < 4; ++j) {
      const int rl  = rowbase + mi*16 + ((lane>>4)<<2) + j;
      const int tok = idxs[e*TPE + rl];
      float* orow = out + (size_t)tok*IN_CH;
#pragma unroll
      for (int ni = 0; ni < 4; ++ni)
        orow[colbase + ni*16 + (lane&15)] = acc[mi][ni][j] + b2v[ni];
    }
  }
}

extern "C" void kernel_launch(void* const* d_in, const int* in_sizes, int n_in,
                              void* d_out, int out_size, void* d_ws, size_t ws_size,
                              hipStream_t stream) {
  const float* x    = (const float*)d_in[0];
  const int*   idxs = (const int*)d_in[1];
  const float* w1w  = (const float*)d_in[2];
  const float* w1b  = (const float*)d_in[3];
  const float* w2w  = (const float*)d_in[4];
  const float* w2b  = (const float*)d_in[5];
  const float* w3w  = (const float*)d_in[6];
  const float* w3b  = (const float*)d_in[7];
  float*  out  = (float*)d_out;
  __bf16* hbuf = (__bf16*)d_ws;   // 128*512*512 bf16 = 64 MB intermediate

  moe_h_kernel<<<dim3(NEXP*32), dim3(512), 0, stream>>>(x, idxs, w1w, w1b, w3w, w3b, hbuf);
  moe_out_kernel<<<dim3(NEXP*32), dim3(512), 0, stream>>>(hbuf, w2w, w2b, idxs, out);
}